// Round 17
// baseline (104.571 us; speedup 1.0000x reference)
//
#include <hip/hip_runtime.h>
#include <hip/hip_bf16.h>

typedef float f32x4 __attribute__((ext_vector_type(4)));
typedef __bf16 bf16x8 __attribute__((ext_vector_type(8)));
typedef __bf16 bf16x4 __attribute__((ext_vector_type(4)));
typedef unsigned short u16;

// Problem dims (fixed): B=128, T=64, H=1024, Hu=512, J=129, N=128, I=64, MJW=64
// ws layout
#define OFF_W1T  0u            // 512x1024 bf16 = 1048576 B  (W1T[n][k] = W1[k][n])
#define OFF_W23B 1048576u      // 144x512 bf16 fragment-order = 147456 B
#define OFF_TS   1196032u      // 8192x512 bf16 = 8388608 B
#define OFF_JWT  9584640u      // 128 x 64(col) x 64(row) f32 = 2097152 B
#define OFF_P0   11681792u     // 8192 f32 = 32768 B

static __device__ __forceinline__ u16 f2bf(float x) {
    __bf16 h = (__bf16)x;
    return __builtin_bit_cast(u16, h);
}

__device__ __forceinline__ void gload16(const void* g, void* l) {
    __builtin_amdgcn_global_load_lds(
        (const __attribute__((address_space(1))) void*)g,
        (__attribute__((address_space(3))) void*)l,
        16, 0, 0);
}

// ---------------------------------------------------------------------------
// prep (unchanged)
// ---------------------------------------------------------------------------
__global__ __launch_bounds__(256) void prep_kernel(
    const float* __restrict__ W1, const float* __restrict__ W2,
    const float* __restrict__ W3,
    __bf16* __restrict__ W1T, __bf16* __restrict__ W23B)
{
    const int t = threadIdx.x;
    if (blockIdx.x < 128) {
        __shared__ __bf16 lds_t[64][72];
        const int kt = blockIdx.x >> 3, nt = blockIdx.x & 7;
        const int k0 = kt * 64, n0 = nt * 64;
        {
            const int kr = t >> 2, c0 = (t & 3) * 16;
            const float* src = W1 + (size_t)(k0 + kr) * 512 + n0 + c0;
            #pragma unroll
            for (int q = 0; q < 4; ++q) {
                float4 v = *(const float4*)(src + q * 4);
                lds_t[kr][c0 + q * 4 + 0] = (__bf16)v.x;
                lds_t[kr][c0 + q * 4 + 1] = (__bf16)v.y;
                lds_t[kr][c0 + q * 4 + 2] = (__bf16)v.z;
                lds_t[kr][c0 + q * 4 + 3] = (__bf16)v.w;
            }
        }
        __syncthreads();
        {
            const int nr = t >> 2, kc = (t & 3) * 16;
            bf16x8 o0, o1;
            #pragma unroll
            for (int j = 0; j < 8; ++j) o0[j] = lds_t[kc + j][nr];
            #pragma unroll
            for (int j = 0; j < 8; ++j) o1[j] = lds_t[kc + 8 + j][nr];
            __bf16* dst = W1T + (size_t)(n0 + nr) * 1024 + k0 + kc;
            *(bf16x8*)(dst)     = o0;
            *(bf16x8*)(dst + 8) = o1;
        }
    } else {
        int g = (blockIdx.x - 128) * 256 + t;   // 0..9215
        if (g < 9216) {
            int n = g >> 6;            // 0..143
            int k8 = (g & 63) * 8;     // 0,8,..,504
            bf16x8 v;
            #pragma unroll
            for (int j = 0; j < 8; ++j) {
                int k = k8 + j;
                float x = 0.0f;
                if (n < 129) x = W2[(size_t)k * 129 + n];
                else if (n == 129) x = W3[k];
                v[j] = (__bf16)x;
            }
            int kk = k8 >> 5, lg = (k8 >> 3) & 3, ct = n >> 4, lr = n & 15;
            *(bf16x8*)&W23B[(((size_t)(kk * 9 + ct)) * 64 + lg * 16 + lr) * 8] = v;
        }
    }
}

// ---------------------------------------------------------------------------
// GEMM1 (unchanged; R14-measured ~22us: ring-3, 3 blocks/CU, vmcnt(4))
// ---------------------------------------------------------------------------
__global__ __launch_bounds__(256, 3) void gemm1_kernel(
    const float* __restrict__ Y, const __bf16* __restrict__ W1T,
    const float* __restrict__ b1, u16* __restrict__ ts)
{
    __shared__ float  As[3][64 * 32];
    __shared__ __bf16 Bs[3][128 * 32];
    const int tid = threadIdx.x;
    const int bid = blockIdx.x;
    const int half = bid >> 8;
    const int b8 = bid & 255;
    const int xcd = b8 & 7;
    const int ii = b8 >> 3;
    const int rb = half * 64 + xcd * 8 + (ii >> 2);
    const int tb = ii & 3;
    const int m0 = rb * 64, n0 = tb * 128;
    const int wid = tid >> 6, lane = tid & 63;
    const int wr = wid >> 1, wc = wid & 1;
    const int lr = lane & 15, lg = lane >> 4;
    const int al = lane >> 3;
    const int au = (lane & 7) ^ al;
    const float* yA0 = Y + (size_t)(m0 + (wid * 2 + 0) * 8 + al) * 1024 + au * 4;
    const float* yA1 = Y + (size_t)(m0 + (wid * 2 + 1) * 8 + al) * 1024 + au * 4;
    const int bl = lane >> 2;
    const int bu = (lane & 3) ^ ((bl >> 1) & 3);
    const __bf16* wB0 = W1T + (size_t)(n0 + (wid * 2 + 0) * 16 + bl) * 1024 + bu * 8;
    const __bf16* wB1 = W1T + (size_t)(n0 + (wid * 2 + 1) * 16 + bl) * 1024 + bu * 8;

    f32x4 acc[2][4];
    #pragma unroll
    for (int m = 0; m < 2; m++)
        #pragma unroll
        for (int n = 0; n < 4; n++) { f32x4 z = {0.f,0.f,0.f,0.f}; acc[m][n] = z; }

#define STAGE(buf, kt) do { \
    gload16(yA0 + (kt) * 32, &As[buf][(wid * 2 + 0) * 256]); \
    gload16(yA1 + (kt) * 32, &As[buf][(wid * 2 + 1) * 256]); \
    gload16(wB0 + (kt) * 32, &Bs[buf][(wid * 2 + 0) * 512]); \
    gload16(wB1 + (kt) * 32, &Bs[buf][(wid * 2 + 1) * 512]); \
} while (0)

#define COMPUTE(buf) do { \
    bf16x8 af[2]; bf16x8 bfr[4]; \
    _Pragma("unroll") \
    for (int m = 0; m < 2; ++m) { \
        const int row = wr * 32 + m * 16 + lr; \
        const int r7 = row & 7; \
        float4 h0 = *(const float4*)&As[buf][row * 32 + (((lg * 2 + 0) ^ r7) * 4)]; \
        float4 h1 = *(const float4*)&As[buf][row * 32 + (((lg * 2 + 1) ^ r7) * 4)]; \
        bf16x8 tt; \
        tt[0]=(__bf16)h0.x; tt[1]=(__bf16)h0.y; tt[2]=(__bf16)h0.z; tt[3]=(__bf16)h0.w; \
        tt[4]=(__bf16)h1.x; tt[5]=(__bf16)h1.y; tt[6]=(__bf16)h1.z; tt[7]=(__bf16)h1.w; \
        af[m] = tt; \
    } \
    _Pragma("unroll") \
    for (int n = 0; n < 4; ++n) { \
        const int rowb = wc * 64 + n * 16 + lr; \
        bfr[n] = *(const bf16x8*)&Bs[buf][rowb * 32 + ((lg ^ ((rowb >> 1) & 3)) * 8)]; \
    } \
    __builtin_amdgcn_s_setprio(1); \
    _Pragma("unroll") \
    for (int m = 0; m < 2; ++m) \
        _Pragma("unroll") \
        for (int n = 0; n < 4; ++n) \
            acc[m][n] = __builtin_amdgcn_mfma_f32_16x16x32_bf16(af[m], bfr[n], acc[m][n], 0, 0, 0); \
    __builtin_amdgcn_s_setprio(0); \
} while (0)

    STAGE(0, 0); STAGE(1, 1);
    {
        int buf = 0, sbuf = 2;
        #pragma unroll 1
        for (int kt = 0; kt < 30; ++kt) {
            asm volatile("s_waitcnt vmcnt(4)" ::: "memory");
            __builtin_amdgcn_s_barrier();
            COMPUTE(buf);
            STAGE(sbuf, kt + 2);
            buf  = (buf  == 2) ? 0 : buf  + 1;
            sbuf = (sbuf == 2) ? 0 : sbuf + 1;
        }
    }
    asm volatile("s_waitcnt vmcnt(4)" ::: "memory");
    __builtin_amdgcn_s_barrier();
    COMPUTE(0);
    asm volatile("s_waitcnt vmcnt(0)" ::: "memory");
    __builtin_amdgcn_s_barrier();
    COMPUTE(1);

    #pragma unroll
    for (int m = 0; m < 2; m++) {
        #pragma unroll
        for (int n = 0; n < 4; n++) {
            int col = n0 + wc * 64 + n * 16 + lr;
            float bias = b1[col];
            #pragma unroll
            for (int j = 0; j < 4; j++) {
                int row = m0 + wr * 32 + m * 16 + lg * 4 + j;
                float v = tanhf(acc[m][n][j] + bias);
                ts[(size_t)row * 512 + col] = f2bf(v);
            }
        }
    }
#undef STAGE
#undef COMPUTE
}

// ---------------------------------------------------------------------------
// band (unchanged): writes jwT[b][c][k] = M_b[k][c] (f32) and p0.
// ---------------------------------------------------------------------------
__global__ __launch_bounds__(256) void band_kernel(
    const u16* __restrict__ ts, const u16* __restrict__ W23B,
    const float* __restrict__ b2, const float* __restrict__ b3,
    float* __restrict__ jwT, float* __restrict__ p0)
{
    const int b = blockIdx.x;
    const int tid = threadIdx.x;
    const int w = tid >> 6, lane = tid & 63;
    const int lr = lane & 15, lg = lane >> 4;
    const int r0 = b * 64 + w * 16;

    f32x4 acc[9];
    #pragma unroll
    for (int ct = 0; ct < 9; ct++) { f32x4 z = {0.f,0.f,0.f,0.f}; acc[ct] = z; }

    #pragma unroll 4
    for (int kk = 0; kk < 16; ++kk) {
        bf16x8 a = *(const bf16x8*)(ts + (size_t)(r0 + lr) * 512 + kk * 32 + lg * 8);
        #pragma unroll
        for (int ct = 0; ct < 9; ct++) {
            bf16x8 bv = *(const bf16x8*)(W23B + ((size_t)(kk * 9 + ct) * 64 + lane) * 8);
            acc[ct] = __builtin_amdgcn_mfma_f32_16x16x32_bf16(a, bv, acc[ct], 0, 0, 0);
        }
    }

    float b3v = b3[0];
    #pragma unroll
    for (int j = 0; j < 4; j++) {
        int rloc = w * 16 + lg * 4 + j;   // row within batch (0..63)
        float v[9];
        float mx = -1e30f;
        #pragma unroll
        for (int ct = 0; ct < 9; ct++) {
            int col = ct * 16 + lr;
            if (col < 129) { float x = acc[ct][j] + b2[col]; v[ct] = x; mx = fmaxf(mx, x); }
            else v[ct] = -1e30f;
        }
        #pragma unroll
        for (int o = 1; o < 16; o <<= 1) mx = fmaxf(mx, __shfl_xor(mx, o));
        float sum = 0.f;
        #pragma unroll
        for (int ct = 0; ct < 9; ct++) {
            int col = ct * 16 + lr;
            if (col < 129) { float e = expf(v[ct] - mx); v[ct] = e; sum += e; }
        }
        #pragma unroll
        for (int o = 1; o < 16; o <<= 1) sum += __shfl_xor(sum, o);
        float inv = 1.0f / sum;
        #pragma unroll
        for (int ct = 0; ct < 9; ct++) {
            int col = ct * 16 + lr;
            int cc = col - 64 + rloc;
            if (col < 129 && cc >= 0 && cc < 64)
                jwT[((size_t)b * 64 + cc) * 64 + rloc] = v[ct] * inv;
        }
        if (lr == 1) {
            float pv = acc[8][j] + b3v;
            p0[b * 64 + rloc] = 1.0f / (1.0f + expf(-pv));
        }
    }
}

// ---------------------------------------------------------------------------
// scan: MFMA matrix-product scan replaces the serial recurrence.
// Per step: P_i = (2^-E * G_i) P_{i-1}, G_i[m][k] = emlo[m,i]*jwT[b][m][k]
// + (k==m)*emhi[m,i]*p0[m]. 4 waves, wave w owns output rows w*16..+15.
// PT stored TRANSPOSED (PT[n][m]=P[m][n], bf16, 128B rows, unit-XOR swizzle
// u^=(row&7)) so it serves directly as next step's B operand. Final:
// out = 1 + ln2*(Eacc + log2(1^T P a0) + 7*idx). Fragment layouts copied
// from band_kernel (verified). wmax parity-double-buffered (race-free).
// ---------------------------------------------------------------------------
__global__ __launch_bounds__(256, 1) void scan_kernel(
    const float* __restrict__ jwT, const float* __restrict__ p0g,
    const float* __restrict__ em, const int* __restrict__ slen,
    float* __restrict__ out)
{
    __shared__ __bf16 Mb[64 * 64];      // Mb[m][k]=jwT[b][m][k], swizzled
    __shared__ __bf16 PT[2][64 * 64];   // PT[buf][n][m], swizzled
    __shared__ float  emT[64][132];     // emT[i][n] = em[b][n][i]
    __shared__ float  p0s[64];
    __shared__ float  wmax[2][4];
    __shared__ float  partial[4][64];

    const int b = blockIdx.x;
    const int t = threadIdx.x;
    const int w = t >> 6, lane = t & 63;
    const int lr = lane & 15, lg = lane >> 4;
    const int idx = slen[b] - 1;

    if (idx <= 0) { if (t == 0) out[b] = 1.0f; return; }

    // ---- stage Mb (bf16 swizzled), emT, p0s ----
    {
        const float4* mg4 = (const float4*)(jwT + (size_t)b * 4096);
        #pragma unroll
        for (int q = 0; q < 4; ++q) {
            int i4 = t + q * 256;
            float4 v = mg4[i4];
            int m = i4 >> 4, k0 = (i4 & 15) * 4;
            int u = (k0 >> 3) ^ (m & 7);
            bf16x4 o; o[0]=(__bf16)v.x; o[1]=(__bf16)v.y; o[2]=(__bf16)v.z; o[3]=(__bf16)v.w;
            *(bf16x4*)&Mb[m * 64 + u * 8 + (k0 & 7)] = o;
        }
        const float4* eg4 = (const float4*)(em + (size_t)b * 8192);
        #pragma unroll
        for (int q = 0; q < 8; ++q) {
            int i4 = t + q * 256;
            float4 v = eg4[i4];
            int n = i4 >> 4, i0 = (i4 & 15) * 4;
            emT[i0 + 0][n] = v.x;
            emT[i0 + 1][n] = v.y;
            emT[i0 + 2][n] = v.z;
            emT[i0 + 3][n] = v.w;
        }
        if (t < 64) p0s[t] = p0g[b * 64 + t];
    }
    __syncthreads();

    const int m = w * 16 + lr;        // this lane's fixed A-row
    const float p0r = p0s[m];

    // ---- init: PT[0] = G_1 transposed; per-wave partial max -> wmax[0] ----
    {
        int n = lane;
        float lmax0 = 0.f;
        #pragma unroll
        for (int mg = 0; mg < 4; ++mg) {
            int m4 = w * 16 + mg * 4;
            bf16x4 o;
            #pragma unroll
            for (int j = 0; j < 4; ++j) {
                int mm = m4 + j;
                float g = emT[1][mm] *
                    (float)Mb[mm * 64 + (((n >> 3) ^ (mm & 7)) * 8) + (n & 7)];
                if (n == mm) g += emT[1][mm + 64] * p0s[mm];
                lmax0 = fmaxf(lmax0, g);
                o[j] = (__bf16)g;
            }
            int u = (m4 >> 3) ^ (n & 7);
            *(bf16x4*)&PT[0][n * 64 + u * 8 + (m4 & 7)] = o;
        }
        #pragma unroll
        for (int o2 = 1; o2 < 64; o2 <<= 1) lmax0 = fmaxf(lmax0, __shfl_xor(lmax0, o2));
        if (lane == 0) wmax[0][w] = lmax0;
    }
    __syncthreads();

    int Eacc = 0;
    int cur = 0;
    #pragma unroll 1
    for (int i = 2; i <= idx; ++i) {
        const int rp = i & 1, wp = rp ^ 1;   // read parity / write parity
        float mx = fmaxf(fmaxf(wmax[rp][0], wmax[rp][1]),
                         fmaxf(wmax[rp][2], wmax[rp][3]));
        int E = ((__float_as_int(mx) >> 23) & 255) - 127;
        Eacc += E;
        float scale = __int_as_float((127 - E) << 23);   // 2^-E exactly
        float emlo_eff = emT[i][m] * scale;
        float emhi_eff = emT[i][m + 64] * p0r * scale;

        // A fragments (G_i rows, built from Mb)
        bf16x8 afr[2];
        #pragma unroll
        for (int kk = 0; kk < 2; ++kk) {
            int kbase = kk * 32 + lg * 8;
            int u = (kbase >> 3) ^ (m & 7);
            bf16x8 mv = *(const bf16x8*)&Mb[m * 64 + u * 8];
            bf16x8 aa;
            #pragma unroll
            for (int j = 0; j < 8; ++j) {
                float h = (float)mv[j] * emlo_eff;
                if (m - kbase == j) h += emhi_eff;
                aa[j] = (__bf16)h;
            }
            afr[kk] = aa;
        }
        // B fragments from PT[cur] + MFMA
        f32x4 acc[4];
        #pragma unroll
        for (int ct = 0; ct < 4; ++ct) { f32x4 z = {0.f,0.f,0.f,0.f}; acc[ct] = z; }
        #pragma unroll
        for (int kk = 0; kk < 2; ++kk) {
            int kbase = kk * 32 + lg * 8;
            #pragma unroll
            for (int ct = 0; ct < 4; ++ct) {
                int row = ct * 16 + lr;
                int u = (kbase >> 3) ^ (row & 7);
                bf16x8 bv = *(const bf16x8*)&PT[cur][row * 64 + u * 8];
                acc[ct] = __builtin_amdgcn_mfma_f32_16x16x32_bf16(afr[kk], bv, acc[ct], 0, 0, 0);
            }
        }
        // epilogue: wave max -> wmax[wp]; write C transposed -> PT[cur^1]
        float lm = 0.f;
        #pragma unroll
        for (int ct = 0; ct < 4; ++ct)
            #pragma unroll
            for (int j = 0; j < 4; ++j) lm = fmaxf(lm, acc[ct][j]);
        #pragma unroll
        for (int o2 = 1; o2 < 64; o2 <<= 1) lm = fmaxf(lm, __shfl_xor(lm, o2));
        if (lane == 0) wmax[wp][w] = lm;
        int m4 = w * 16 + lg * 4;
        #pragma unroll
        for (int ct = 0; ct < 4; ++ct) {
            int row = ct * 16 + lr;
            bf16x4 o;
            #pragma unroll
            for (int j = 0; j < 4; ++j) o[j] = (__bf16)acc[ct][j];
            int u = (m4 >> 3) ^ (row & 7);
            *(bf16x4*)&PT[cur ^ 1][row * 64 + u * 8 + (m4 & 7)] = o;
        }
        __syncthreads();
        cur ^= 1;
    }

    // ---- final: total = sum_c a0[c] * rowsum(PT[cur] row c) ----
    {
        int c = lane;
        float s = 0.f;
        #pragma unroll
        for (int mg = 0; mg < 4; ++mg) {
            int m4 = w * 16 + mg * 4;
            int u = (m4 >> 3) ^ (c & 7);
            bf16x4 v4 = *(const bf16x4*)&PT[cur][c * 64 + u * 8 + (m4 & 7)];
            s += (float)v4[0] + (float)v4[1] + (float)v4[2] + (float)v4[3];
        }
        partial[w][c] = s;
    }
    __syncthreads();
    if (w == 0) {
        int c = lane;
        float tot = partial[0][c] + partial[1][c] + partial[2][c] + partial[3][c];
        float a0c = emT[0][c] + emT[0][c + 64];
        float v = tot * a0c;
        #pragma unroll
        for (int o2 = 1; o2 < 64; o2 <<= 1) v += __shfl_xor(v, o2);
        if (c == 0)
            out[b] = 1.0f + 0.6931471805599453f *
                     ((float)Eacc + __log2f(v) + 7.0f * (float)idx);
    }
}

extern "C" void kernel_launch(void* const* d_in, const int* in_sizes, int n_in,
                              void* d_out, int out_size, void* d_ws, size_t ws_size,
                              hipStream_t stream)
{
    const float* Y   = (const float*)d_in[0];
    const float* em  = (const float*)d_in[1];
    const int*   sl  = (const int*)d_in[2];
    const float* W1  = (const float*)d_in[3];
    const float* b1  = (const float*)d_in[4];
    const float* W2  = (const float*)d_in[5];
    const float* b2  = (const float*)d_in[6];
    const float* W3  = (const float*)d_in[7];
    const float* b3  = (const float*)d_in[8];
    float* out = (float*)d_out;
    char* ws = (char*)d_ws;

    __bf16* W1T  = (__bf16*)(ws + OFF_W1T);
    __bf16* W23B = (__bf16*)(ws + OFF_W23B);
    u16*    ts   = (u16*)(ws + OFF_TS);
    float*  jwT  = (float*)(ws + OFF_JWT);
    float*  p0   = (float*)(ws + OFF_P0);

    prep_kernel<<<164, 256, 0, stream>>>(W1, W2, W3, W1T, W23B);
    gemm1_kernel<<<512, 256, 0, stream>>>(Y, W1T, b1, ts);
    band_kernel<<<128, 256, 0, stream>>>(ts, (const u16*)W23B, b2, b3, jwT, p0);
    scan_kernel<<<128, 256, 0, stream>>>(jwT, p0, em, sl, out);
}